// Round 3
// baseline (692.873 us; speedup 1.0000x reference)
//
#include <hip/hip_runtime.h>
#include <stdint.h>

// MPNN layer, dst-sorted edge processing, LDS-overlay version:
//  - counting-sort edges by dst
//  - msg kernel: 64 sorted edges/block, bf16 MFMA MLP; Hs and OUT tiles
//    overlay the A tile per-wave-strip (wave-private until final barrier)
//    -> 24.3 KB LDS -> 6 blocks/CU. Segmented LDS reduction -> few atomics.
//  - upd kernel: node MLP + residual, same overlay trick (5 blocks/CU).

#define N_NODES 100000
#define N_EDGES 800000
#define NODE_DIM 64
#define EDGE_DIM 32
#define HIDDEN 128
#define LN_EPS 1e-5f

#define PA 168   // msg A-tile pitch (bf16 elems), 160 data cols
#define PH 136   // Hs / OUT strip pitch (bf16 elems), 128 data cols
#define PU 200   // upd A-tile pitch (bf16 elems), 192 data cols

#define NB_SCAN ((N_NODES + 1023) / 1024)   // 98

typedef __attribute__((ext_vector_type(8))) short short8;
typedef __attribute__((ext_vector_type(4))) float f32x4;

static __device__ __forceinline__ uint16_t f2bf(float f) {
  uint32_t u = __float_as_uint(f);
  return (uint16_t)((u + 0x7FFFu + ((u >> 16) & 1u)) >> 16);
}

// ---------------- fused prepass: cvt_x + hist + pack all weights ----------------
// block ranges: [0, 6250) cvt_x quads; [6250, 9375) hist; [9375, 9647) packs.

#define PREP_CVT_BLKS 6250
#define PREP_HIST_BLKS 3125

__global__ void prep_kernel(const float* __restrict__ x, uint16_t* __restrict__ xb,
                            const int* __restrict__ ei, int* __restrict__ cnt,
                            const float* __restrict__ W1, uint16_t* __restrict__ W1p,
                            const float* __restrict__ W2, uint16_t* __restrict__ W2p,
                            const float* __restrict__ Wu1, uint16_t* __restrict__ Wu1p,
                            const float* __restrict__ Wu2, uint16_t* __restrict__ Wu2p) {
  int b = blockIdx.x;
  if (b < PREP_CVT_BLKS) {
    int i = b * 256 + threadIdx.x;           // quad index
    if (i * 4 < N_NODES * NODE_DIM) {
      float4 f = *(const float4*)(x + (size_t)i * 4);
      ushort4 o;
      o.x = f2bf(f.x); o.y = f2bf(f.y); o.z = f2bf(f.z); o.w = f2bf(f.w);
      *(ushort4*)(xb + (size_t)i * 4) = o;
    }
    return;
  }
  if (b < PREP_CVT_BLKS + PREP_HIST_BLKS) {
    int e = (b - PREP_CVT_BLKS) * 256 + threadIdx.x;
    if (e < N_EDGES) atomicAdd(&cnt[ei[N_EDGES + e]], 1);
    return;
  }
  int i = (b - PREP_CVT_BLKS - PREP_HIST_BLKS) * 256 + threadIdx.x;
  const float* W; uint16_t* dst; int K, C;
  if (i < 20480)      { W = W1;  dst = W1p;  K = 160; C = 128; }
  else if (i < 36864) { W = W2;  dst = W2p;  K = 128; C = 128; i -= 20480; }
  else if (i < 61440) { W = Wu1; dst = Wu1p; K = 192; C = 128; i -= 36864; }
  else if (i < 69632) { W = Wu2; dst = Wu2p; K = 128; C = 64;  i -= 61440; }
  else return;
  int k = i / C, c = i % C;
  dst[(((k >> 5) * C + c) * 4 + ((k >> 3) & 3)) * 8 + (k & 7)] = f2bf(W[i]);
}

// ---------------- counting sort by dst ----------------

__global__ __launch_bounds__(256) void scan_blk(const int* __restrict__ cnt,
                                                int* __restrict__ offs,
                                                int* __restrict__ bsum) {
  __shared__ int wsum[4];
  int tid = threadIdx.x;
  int base = blockIdx.x * 1024 + tid * 4;
  int v0 = 0, v1 = 0, v2 = 0, v3 = 0;
  if (base < N_NODES) v0 = cnt[base];
  if (base + 1 < N_NODES) v1 = cnt[base + 1];
  if (base + 2 < N_NODES) v2 = cnt[base + 2];
  if (base + 3 < N_NODES) v3 = cnt[base + 3];
  int tsum = v0 + v1 + v2 + v3;
  int lane = tid & 63, wid = tid >> 6;
  int s = tsum;
  #pragma unroll
  for (int d = 1; d < 64; d <<= 1) {
    int t = __shfl_up(s, d);
    if (lane >= d) s += t;
  }
  if (lane == 63) wsum[wid] = s;
  __syncthreads();
  int woff = 0;
  for (int w = 0; w < wid; ++w) woff += wsum[w];
  int excl = woff + s - tsum;
  if (base < N_NODES) {
    int run = excl;
    offs[base] = run; run += v0;
    if (base + 1 < N_NODES) { offs[base + 1] = run; run += v1; }
    if (base + 2 < N_NODES) { offs[base + 2] = run; run += v2; }
    if (base + 3 < N_NODES) { offs[base + 3] = run; run += v3; }
  }
  if (tid == 255) bsum[blockIdx.x] = woff + s;
}

__global__ void scan_top(int* __restrict__ bsum) {
  __shared__ int sh[128];
  int tid = threadIdx.x;
  int v = (tid < NB_SCAN) ? bsum[tid] : 0;
  int orig = v;
  sh[tid] = v;
  __syncthreads();
  for (int d = 1; d < 128; d <<= 1) {
    int t = (tid >= d) ? sh[tid - d] : 0;
    __syncthreads();
    v += t;
    sh[tid] = v;
    __syncthreads();
  }
  if (tid < NB_SCAN) bsum[tid] = v - orig;
}

__global__ void scan_add(const int* __restrict__ offs, const int* __restrict__ bsum,
                         int* __restrict__ cursor) {
  int i = blockIdx.x * 256 + threadIdx.x;
  if (i < N_NODES) cursor[i] = offs[i] + bsum[i >> 10];
}

__global__ void scatter_edges(const int* __restrict__ ei, int* __restrict__ cursor,
                              int* __restrict__ src_s, int* __restrict__ dst_s,
                              int* __restrict__ eid_s) {
  int e = blockIdx.x * 256 + threadIdx.x;
  if (e < N_EDGES) {
    int s = ei[e], d = ei[N_EDGES + e];
    int p = atomicAdd(&cursor[d], 1);
    src_s[p] = s; dst_s[p] = d; eid_s[p] = e;
  }
}

// ---------------- message kernel (sorted edges, overlaid LDS) ----------------

__global__ __launch_bounds__(256, 6) void msg_kernel(
    const int* __restrict__ src_s, const int* __restrict__ dst_s,
    const int* __restrict__ eid_s,
    const float* __restrict__ ea, const uint16_t* __restrict__ xb,
    const uint16_t* __restrict__ W1p, const float* __restrict__ b1,
    const float* __restrict__ g1, const float* __restrict__ be1,
    const uint16_t* __restrict__ W2p, const float* __restrict__ b2,
    float* __restrict__ agg) {
  // A tile 64 x PA (21504 B). Hs and bf16 OUT overlay per-wave strips:
  // strip base = r0*PA, row pitch PH (16*PH=2176 <= 16*PA=2688).
  // Wave-private until the final barrier (writes data-depend on the MFMAs
  // that consumed the previous contents), so no extra syncs needed.
  __shared__ __align__(16) uint16_t A[64 * PA];
  __shared__ int ssrc[64], sdst[64], seid[64];
  __shared__ float sb1[128], sg[128], sbe[128], sb2[128];

  const int tid = threadIdx.x;
  const int e0 = blockIdx.x * 64;

  if (tid < 64) ssrc[tid] = src_s[e0 + tid];
  else if (tid < 128) sdst[tid - 64] = dst_s[e0 + tid - 64];
  else if (tid < 192) seid[tid - 128] = eid_s[e0 + tid - 128];
  if (tid < 128) { sb1[tid] = b1[tid]; sg[tid] = g1[tid]; }
  else { sbe[tid - 128] = be1[tid - 128]; sb2[tid - 128] = b2[tid - 128]; }
  __syncthreads();

  // gather x[src], x[dst] (bf16 rows, 8x16B) + convert edge_attr row
  #pragma unroll
  for (int it = 0; it < 2; ++it) {
    int u = tid + it * 256;
    int e = u >> 3, q = u & 7;
    uint4 vs = *(const uint4*)(xb + (size_t)ssrc[e] * 64 + q * 8);
    *(uint4*)(&A[e * PA + q * 8]) = vs;
    uint4 vd = *(const uint4*)(xb + (size_t)sdst[e] * 64 + q * 8);
    *(uint4*)(&A[e * PA + 64 + q * 8]) = vd;
    float4 f = *(const float4*)(ea + (size_t)seid[e] * EDGE_DIM + q * 4);
    ushort4 o;
    o.x = f2bf(f.x); o.y = f2bf(f.y); o.z = f2bf(f.z); o.w = f2bf(f.w);
    *(ushort4*)(&A[e * PA + 128 + q * 4]) = o;
  }
  __syncthreads();

  const int wid = tid >> 6, lane = tid & 63;
  const int lrow = lane & 15, lk = lane >> 4;
  const int r0 = wid * 16;

  // GEMM1: (64x160) @ (160x128)
  f32x4 acc[8] = {};
  const uint16_t* Abase = &A[(r0 + lrow) * PA + lk * 8];
  #pragma unroll
  for (int c = 0; c < 5; ++c) {
    short8 a = *(const short8*)(Abase + c * 32);
    #pragma unroll
    for (int n = 0; n < 8; ++n) {
      short8 b = *(const short8*)(W1p + ((size_t)((c * 128) + (n * 16 + lrow)) * 4 + lk) * 8);
      acc[n] = __builtin_amdgcn_mfma_f32_16x16x32_bf16(a, b, acc[n], 0, 0, 0);
    }
  }

  // bias + LayerNorm + SiLU -> Hs (bf16, strip overlay on A)
  uint16_t* strip = &A[r0 * PA];
  #pragma unroll
  for (int reg = 0; reg < 4; ++reg) {
    float v[8];
    float s = 0.f, ss = 0.f;
    #pragma unroll
    for (int n = 0; n < 8; ++n) {
      v[n] = acc[n][reg] + sb1[n * 16 + lrow];
      s += v[n]; ss += v[n] * v[n];
    }
    #pragma unroll
    for (int m = 1; m <= 8; m <<= 1) {
      s += __shfl_xor(s, m);
      ss += __shfl_xor(ss, m);
    }
    float mu = s * (1.f / 128.f);
    float rstd = rsqrtf(ss * (1.f / 128.f) - mu * mu + LN_EPS);
    uint16_t* hrow = strip + (lk * 4 + reg) * PH;
    #pragma unroll
    for (int n = 0; n < 8; ++n) {
      int col = n * 16 + lrow;
      float h = (v[n] - mu) * rstd * sg[col] + sbe[col];
      h = h / (1.f + __expf(-h));
      hrow[col] = f2bf(h);
    }
  }

  // GEMM2: (64x128) @ (128x128), A-fragments from Hs strip
  f32x4 acc2[8] = {};
  const uint16_t* Hbase = strip + lrow * PH + lk * 8;
  #pragma unroll
  for (int c = 0; c < 4; ++c) {
    short8 a = *(const short8*)(Hbase + c * 32);
    #pragma unroll
    for (int n = 0; n < 8; ++n) {
      short8 b = *(const short8*)(W2p + ((size_t)((c * 128) + (n * 16 + lrow)) * 4 + lk) * 8);
      acc2[n] = __builtin_amdgcn_mfma_f32_16x16x32_bf16(a, b, acc2[n], 0, 0, 0);
    }
  }

  // bias -> bf16 OUT (same strip overlay; safe: values depend on all Hs reads)
  #pragma unroll
  for (int reg = 0; reg < 4; ++reg) {
    uint16_t* orow = strip + (lk * 4 + reg) * PH;
    #pragma unroll
    for (int n = 0; n < 8; ++n) {
      int col = n * 16 + lrow;
      orow[col] = f2bf(acc2[n][reg] + sb2[col]);
    }
  }
  __syncthreads();

  // segmented reduction over sorted dst: one atomic per (run, col)
  {
    int c = tid & 127;
    int rlo = (tid >> 7) * 32;
    #define LD_OUT(r) __uint_as_float(((uint32_t)A[((r) & ~15) * PA + ((r) & 15) * PH + c]) << 16)
    float run = LD_OUT(rlo);
    int cur = sdst[rlo];
    for (int r = rlo + 1; r < rlo + 32; ++r) {
      int d = sdst[r];           // uniform across wave -> no divergence
      float v = LD_OUT(r);
      if (d != cur) {
        atomicAdd(agg + (size_t)cur * HIDDEN + c, run);
        run = v; cur = d;
      } else {
        run += v;
      }
    }
    atomicAdd(agg + (size_t)cur * HIDDEN + c, run);
    #undef LD_OUT
  }
}

// ---------------- update kernel (overlaid LDS) ----------------

__global__ __launch_bounds__(256, 5) void upd_kernel(
    const float* __restrict__ x, const uint16_t* __restrict__ xb,
    const float* __restrict__ agg,
    const uint16_t* __restrict__ Wu1p, const float* __restrict__ b1,
    const float* __restrict__ g1, const float* __restrict__ be1,
    const uint16_t* __restrict__ Wu2p, const float* __restrict__ b2,
    float* __restrict__ out) {
  __shared__ __align__(16) uint16_t A[64 * PU];
  __shared__ float sb1[128], sg[128], sbe[128], sb2[64];

  const int tid = threadIdx.x;
  const int n0 = blockIdx.x * 64;

  if (tid < 128) { sb1[tid] = b1[tid]; sg[tid] = g1[tid]; }
  else { sbe[tid - 128] = be1[tid - 128]; if (tid < 192) sb2[tid - 128] = b2[tid - 128]; }

  #pragma unroll
  for (int it = 0; it < 2; ++it) {
    int u = tid + it * 256;
    int r = u >> 3, q = u & 7;
    int node = min(n0 + r, N_NODES - 1);
    uint4 vs = *(const uint4*)(xb + (size_t)node * 64 + q * 8);
    *(uint4*)(&A[r * PU + q * 8]) = vs;
  }
  #pragma unroll
  for (int it = 0; it < 8; ++it) {
    int u = tid + it * 256;
    int r = u >> 5, q = u & 31;
    int node = min(n0 + r, N_NODES - 1);
    float4 f = *(const float4*)(agg + (size_t)node * HIDDEN + q * 4);
    ushort4 o;
    o.x = f2bf(f.x); o.y = f2bf(f.y); o.z = f2bf(f.z); o.w = f2bf(f.w);
    *(ushort4*)(&A[r * PU + 64 + q * 4]) = o;
  }
  __syncthreads();

  const int wid = tid >> 6, lane = tid & 63;
  const int lrow = lane & 15, lk = lane >> 4;
  const int r0 = wid * 16;

  // GEMM1: (64x192) @ (192x128)
  f32x4 acc[8] = {};
  const uint16_t* Abase = &A[(r0 + lrow) * PU + lk * 8];
  #pragma unroll
  for (int c = 0; c < 6; ++c) {
    short8 a = *(const short8*)(Abase + c * 32);
    #pragma unroll
    for (int n = 0; n < 8; ++n) {
      short8 b = *(const short8*)(Wu1p + ((size_t)((c * 128) + (n * 16 + lrow)) * 4 + lk) * 8);
      acc[n] = __builtin_amdgcn_mfma_f32_16x16x32_bf16(a, b, acc[n], 0, 0, 0);
    }
  }

  // bias + LN + SiLU -> Hs (strip overlay on A)
  uint16_t* strip = &A[r0 * PU];
  #pragma unroll
  for (int reg = 0; reg < 4; ++reg) {
    float v[8];
    float s = 0.f, ss = 0.f;
    #pragma unroll
    for (int n = 0; n < 8; ++n) {
      v[n] = acc[n][reg] + sb1[n * 16 + lrow];
      s += v[n]; ss += v[n] * v[n];
    }
    #pragma unroll
    for (int m = 1; m <= 8; m <<= 1) {
      s += __shfl_xor(s, m);
      ss += __shfl_xor(ss, m);
    }
    float mu = s * (1.f / 128.f);
    float rstd = rsqrtf(ss * (1.f / 128.f) - mu * mu + LN_EPS);
    uint16_t* hrow = strip + (lk * 4 + reg) * PH;
    #pragma unroll
    for (int n = 0; n < 8; ++n) {
      int col = n * 16 + lrow;
      float h = (v[n] - mu) * rstd * sg[col] + sbe[col];
      h = h / (1.f + __expf(-h));
      hrow[col] = f2bf(h);
    }
  }

  // GEMM2: (64x128) @ (128x64)
  f32x4 acc2[4] = {};
  const uint16_t* Hbase = strip + lrow * PH + lk * 8;
  #pragma unroll
  for (int c = 0; c < 4; ++c) {
    short8 a = *(const short8*)(Hbase + c * 32);
    #pragma unroll
    for (int n = 0; n < 4; ++n) {
      short8 b = *(const short8*)(Wu2p + ((size_t)((c * 64) + (n * 16 + lrow)) * 4 + lk) * 8);
      acc2[n] = __builtin_amdgcn_mfma_f32_16x16x32_bf16(a, b, acc2[n], 0, 0, 0);
    }
  }

  // residual + bias + store f32
  #pragma unroll
  for (int reg = 0; reg < 4; ++reg) {
    int node = n0 + r0 + lk * 4 + reg;
    if (node < N_NODES) {
      #pragma unroll
      for (int n = 0; n < 4; ++n) {
        int col = n * 16 + lrow;
        out[(size_t)node * 64 + col] =
            x[(size_t)node * 64 + col] + acc2[n][reg] + sb2[col];
      }
    }
  }
}

extern "C" void kernel_launch(void* const* d_in, const int* in_sizes, int n_in,
                              void* d_out, int out_size, void* d_ws, size_t ws_size,
                              hipStream_t stream) {
  const float* x   = (const float*)d_in[0];
  const int*   ei  = (const int*)d_in[1];
  const float* ea  = (const float*)d_in[2];
  const float* W1  = (const float*)d_in[3];
  const float* b1  = (const float*)d_in[4];
  const float* g1  = (const float*)d_in[5];
  const float* be1 = (const float*)d_in[6];
  const float* W2  = (const float*)d_in[7];
  const float* b2  = (const float*)d_in[8];
  const float* Wu1 = (const float*)d_in[9];
  const float* bu1 = (const float*)d_in[10];
  const float* gu  = (const float*)d_in[11];
  const float* beu = (const float*)d_in[12];
  const float* Wu2 = (const float*)d_in[13];
  const float* bu2 = (const float*)d_in[14];
  float* out = (float*)d_out;

  char* ws = (char*)d_ws;
  float*    agg    = (float*)ws;                      // 51,200,000
  uint16_t* xb     = (uint16_t*)(ws + 51200000);      // 12,800,000
  uint16_t* W1p    = (uint16_t*)(ws + 64000000);      // 40,960
  uint16_t* W2p    = (uint16_t*)(ws + 64040960);      // 32,768
  uint16_t* Wu1p   = (uint16_t*)(ws + 64073728);      // 49,152
  uint16_t* Wu2p   = (uint16_t*)(ws + 64122880);      // 16,384
  int*      cnt    = (int*)(ws + 64139264);           // 400,000
  int*      offs   = (int*)(ws + 64539264);           // 400,000
  int*      cursor = (int*)(ws + 64939264);           // 400,000
  int*      bsum   = (int*)(ws + 65339264);           // 512
  int*      src_s  = (int*)(ws + 65339776);           // 3,200,000
  int*      dst_s  = (int*)(ws + 68539776);           // 3,200,000
  int*      eid_s  = (int*)(ws + 71739776);           // 3,200,000  (end ~74.9 MB)

  hipMemsetAsync(agg, 0, (size_t)N_NODES * HIDDEN * 4, stream);
  hipMemsetAsync(cnt, 0, (size_t)N_NODES * 4, stream);

  prep_kernel<<<PREP_CVT_BLKS + PREP_HIST_BLKS + 272, 256, 0, stream>>>(
      x, xb, ei, cnt, W1, W1p, W2, W2p, Wu1, Wu1p, Wu2, Wu2p);

  scan_blk<<<NB_SCAN, 256, 0, stream>>>(cnt, offs, bsum);
  scan_top<<<1, 128, 0, stream>>>(bsum);
  scan_add<<<(N_NODES + 255) / 256, 256, 0, stream>>>(offs, bsum, cursor);
  scatter_edges<<<(N_EDGES + 255) / 256, 256, 0, stream>>>(ei, cursor, src_s, dst_s, eid_s);

  msg_kernel<<<N_EDGES / 64, 256, 0, stream>>>(src_s, dst_s, eid_s, ea, xb,
                                               W1p, b1, g1, be1, W2p, b2, agg);
  upd_kernel<<<(N_NODES + 63) / 64, 256, 0, stream>>>(x, xb, agg, Wu1p, bu1, gu, beu,
                                                      Wu2p, bu2, out);
}

// Round 5
// 467.358 us; speedup vs baseline: 1.4825x; 1.4825x over previous
//
#include <hip/hip_runtime.h>
#include <stdint.h>

// MPNN layer, dst-sorted edge processing, LDS-overlay version (R3 structure):
//  - counting-sort edges by dst
//  - msg kernel: 64 sorted edges/block, bf16 MFMA MLP; Hs and OUT tiles
//    overlay the A tile per-wave-strip -> 24.3 KB LDS (6 blocks/CU by LDS).
//    NO min-waves launch bound: (256,6) forced VGPR 80->40 and spilled the
//    64-f32 accumulator set (R3: 1.7 GB scratch traffic); (256,4) + barrier
//    restructure diverged post-timing (R4). Natural VGPR (~80) allows
//    6 waves/SIMD anyway.
//  - upd kernel: node MLP + residual, same overlay.

#define N_NODES 100000
#define N_EDGES 800000
#define NODE_DIM 64
#define EDGE_DIM 32
#define HIDDEN 128
#define LN_EPS 1e-5f

#define PA 168   // msg A-tile pitch (bf16 elems), 160 data cols
#define PH 136   // Hs / OUT strip pitch (bf16 elems), 128 data cols
#define PU 200   // upd A-tile pitch (bf16 elems), 192 data cols

#define NB_SCAN ((N_NODES + 1023) / 1024)   // 98

typedef __attribute__((ext_vector_type(8))) short short8;
typedef __attribute__((ext_vector_type(4))) float f32x4;

static __device__ __forceinline__ uint16_t f2bf(float f) {
  uint32_t u = __float_as_uint(f);
  return (uint16_t)((u + 0x7FFFu + ((u >> 16) & 1u)) >> 16);
}

// ---------------- fused prepass: cvt_x + hist + pack all weights ----------------

#define PREP_CVT_BLKS 6250
#define PREP_HIST_BLKS 3125

__global__ void prep_kernel(const float* __restrict__ x, uint16_t* __restrict__ xb,
                            const int* __restrict__ ei, int* __restrict__ cnt,
                            const float* __restrict__ W1, uint16_t* __restrict__ W1p,
                            const float* __restrict__ W2, uint16_t* __restrict__ W2p,
                            const float* __restrict__ Wu1, uint16_t* __restrict__ Wu1p,
                            const float* __restrict__ Wu2, uint16_t* __restrict__ Wu2p) {
  int b = blockIdx.x;
  if (b < PREP_CVT_BLKS) {
    int i = b * 256 + threadIdx.x;           // quad index
    if (i * 4 < N_NODES * NODE_DIM) {
      float4 f = *(const float4*)(x + (size_t)i * 4);
      ushort4 o;
      o.x = f2bf(f.x); o.y = f2bf(f.y); o.z = f2bf(f.z); o.w = f2bf(f.w);
      *(ushort4*)(xb + (size_t)i * 4) = o;
    }
    return;
  }
  if (b < PREP_CVT_BLKS + PREP_HIST_BLKS) {
    int e = (b - PREP_CVT_BLKS) * 256 + threadIdx.x;
    if (e < N_EDGES) atomicAdd(&cnt[ei[N_EDGES + e]], 1);
    return;
  }
  int i = (b - PREP_CVT_BLKS - PREP_HIST_BLKS) * 256 + threadIdx.x;
  const float* W; uint16_t* dst; int K, C;
  if (i < 20480)      { W = W1;  dst = W1p;  K = 160; C = 128; }
  else if (i < 36864) { W = W2;  dst = W2p;  K = 128; C = 128; i -= 20480; }
  else if (i < 61440) { W = Wu1; dst = Wu1p; K = 192; C = 128; i -= 36864; }
  else if (i < 69632) { W = Wu2; dst = Wu2p; K = 128; C = 64;  i -= 61440; }
  else return;
  int k = i / C, c = i % C;
  dst[(((k >> 5) * C + c) * 4 + ((k >> 3) & 3)) * 8 + (k & 7)] = f2bf(W[i]);
}

// ---------------- counting sort by dst ----------------

__global__ __launch_bounds__(256) void scan_blk(const int* __restrict__ cnt,
                                                int* __restrict__ offs,
                                                int* __restrict__ bsum) {
  __shared__ int wsum[4];
  int tid = threadIdx.x;
  int base = blockIdx.x * 1024 + tid * 4;
  int v0 = 0, v1 = 0, v2 = 0, v3 = 0;
  if (base < N_NODES) v0 = cnt[base];
  if (base + 1 < N_NODES) v1 = cnt[base + 1];
  if (base + 2 < N_NODES) v2 = cnt[base + 2];
  if (base + 3 < N_NODES) v3 = cnt[base + 3];
  int tsum = v0 + v1 + v2 + v3;
  int lane = tid & 63, wid = tid >> 6;
  int s = tsum;
  #pragma unroll
  for (int d = 1; d < 64; d <<= 1) {
    int t = __shfl_up(s, d);
    if (lane >= d) s += t;
  }
  if (lane == 63) wsum[wid] = s;
  __syncthreads();
  int woff = 0;
  for (int w = 0; w < wid; ++w) woff += wsum[w];
  int excl = woff + s - tsum;
  if (base < N_NODES) {
    int run = excl;
    offs[base] = run; run += v0;
    if (base + 1 < N_NODES) { offs[base + 1] = run; run += v1; }
    if (base + 2 < N_NODES) { offs[base + 2] = run; run += v2; }
    if (base + 3 < N_NODES) { offs[base + 3] = run; run += v3; }
  }
  if (tid == 255) bsum[blockIdx.x] = woff + s;
}

__global__ void scan_top(int* __restrict__ bsum) {
  __shared__ int sh[128];
  int tid = threadIdx.x;
  int v = (tid < NB_SCAN) ? bsum[tid] : 0;
  int orig = v;
  sh[tid] = v;
  __syncthreads();
  for (int d = 1; d < 128; d <<= 1) {
    int t = (tid >= d) ? sh[tid - d] : 0;
    __syncthreads();
    v += t;
    sh[tid] = v;
    __syncthreads();
  }
  if (tid < NB_SCAN) bsum[tid] = v - orig;
}

__global__ void scan_add(const int* __restrict__ offs, const int* __restrict__ bsum,
                         int* __restrict__ cursor) {
  int i = blockIdx.x * 256 + threadIdx.x;
  if (i < N_NODES) cursor[i] = offs[i] + bsum[i >> 10];
}

__global__ void scatter_edges(const int* __restrict__ ei, int* __restrict__ cursor,
                              int* __restrict__ src_s, int* __restrict__ dst_s,
                              int* __restrict__ eid_s) {
  int e = blockIdx.x * 256 + threadIdx.x;
  if (e < N_EDGES) {
    int s = ei[e], d = ei[N_EDGES + e];
    int p = atomicAdd(&cursor[d], 1);
    src_s[p] = s; dst_s[p] = d; eid_s[p] = e;
  }
}

// ---------------- message kernel (sorted edges, overlaid LDS) ----------------

__global__ __launch_bounds__(256) void msg_kernel(
    const int* __restrict__ src_s, const int* __restrict__ dst_s,
    const int* __restrict__ eid_s,
    const float* __restrict__ ea, const uint16_t* __restrict__ xb,
    const uint16_t* __restrict__ W1p, const float* __restrict__ b1,
    const float* __restrict__ g1, const float* __restrict__ be1,
    const uint16_t* __restrict__ W2p, const float* __restrict__ b2,
    float* __restrict__ agg) {
  // A tile 64 x PA (21504 B). Hs and bf16 OUT overlay per-wave strips:
  // strip base = r0*PA, row pitch PH (16*PH=2176 <= 16*PA=2688).
  // Wave-private until the final barrier.
  __shared__ __align__(16) uint16_t A[64 * PA];
  __shared__ int ssrc[64], sdst[64], seid[64];
  __shared__ float sb1[128], sg[128], sbe[128], sb2[128];

  const int tid = threadIdx.x;
  const int e0 = blockIdx.x * 64;

  if (tid < 64) ssrc[tid] = src_s[e0 + tid];
  else if (tid < 128) sdst[tid - 64] = dst_s[e0 + tid - 64];
  else if (tid < 192) seid[tid - 128] = eid_s[e0 + tid - 128];
  if (tid < 128) { sb1[tid] = b1[tid]; sg[tid] = g1[tid]; }
  else { sbe[tid - 128] = be1[tid - 128]; sb2[tid - 128] = b2[tid - 128]; }
  __syncthreads();

  // gather x[src], x[dst] (bf16 rows, 8x16B) + convert edge_attr row
  #pragma unroll
  for (int it = 0; it < 2; ++it) {
    int u = tid + it * 256;
    int e = u >> 3, q = u & 7;
    uint4 vs = *(const uint4*)(xb + (size_t)ssrc[e] * 64 + q * 8);
    *(uint4*)(&A[e * PA + q * 8]) = vs;
    uint4 vd = *(const uint4*)(xb + (size_t)sdst[e] * 64 + q * 8);
    *(uint4*)(&A[e * PA + 64 + q * 8]) = vd;
    float4 f = *(const float4*)(ea + (size_t)seid[e] * EDGE_DIM + q * 4);
    ushort4 o;
    o.x = f2bf(f.x); o.y = f2bf(f.y); o.z = f2bf(f.z); o.w = f2bf(f.w);
    *(ushort4*)(&A[e * PA + 128 + q * 4]) = o;
  }
  __syncthreads();

  const int wid = tid >> 6, lane = tid & 63;
  const int lrow = lane & 15, lk = lane >> 4;
  const int r0 = wid * 16;

  // GEMM1: (64x160) @ (160x128)
  f32x4 acc[8] = {};
  const uint16_t* Abase = &A[(r0 + lrow) * PA + lk * 8];
  #pragma unroll
  for (int c = 0; c < 5; ++c) {
    short8 a = *(const short8*)(Abase + c * 32);
    #pragma unroll
    for (int n = 0; n < 8; ++n) {
      short8 b = *(const short8*)(W1p + ((size_t)((c * 128) + (n * 16 + lrow)) * 4 + lk) * 8);
      acc[n] = __builtin_amdgcn_mfma_f32_16x16x32_bf16(a, b, acc[n], 0, 0, 0);
    }
  }

  // bias + LayerNorm + SiLU -> Hs (bf16, strip overlay on A)
  uint16_t* strip = &A[r0 * PA];
  #pragma unroll
  for (int reg = 0; reg < 4; ++reg) {
    float v[8];
    float s = 0.f, ss = 0.f;
    #pragma unroll
    for (int n = 0; n < 8; ++n) {
      v[n] = acc[n][reg] + sb1[n * 16 + lrow];
      s += v[n]; ss += v[n] * v[n];
    }
    #pragma unroll
    for (int m = 1; m <= 8; m <<= 1) {
      s += __shfl_xor(s, m);
      ss += __shfl_xor(ss, m);
    }
    float mu = s * (1.f / 128.f);
    float rstd = rsqrtf(ss * (1.f / 128.f) - mu * mu + LN_EPS);
    uint16_t* hrow = strip + (lk * 4 + reg) * PH;
    #pragma unroll
    for (int n = 0; n < 8; ++n) {
      int col = n * 16 + lrow;
      float h = (v[n] - mu) * rstd * sg[col] + sbe[col];
      h = h / (1.f + __expf(-h));
      hrow[col] = f2bf(h);
    }
  }

  // GEMM2: (64x128) @ (128x128), A-fragments from Hs strip
  f32x4 acc2[8] = {};
  const uint16_t* Hbase = strip + lrow * PH + lk * 8;
  #pragma unroll
  for (int c = 0; c < 4; ++c) {
    short8 a = *(const short8*)(Hbase + c * 32);
    #pragma unroll
    for (int n = 0; n < 8; ++n) {
      short8 b = *(const short8*)(W2p + ((size_t)((c * 128) + (n * 16 + lrow)) * 4 + lk) * 8);
      acc2[n] = __builtin_amdgcn_mfma_f32_16x16x32_bf16(a, b, acc2[n], 0, 0, 0);
    }
  }

  // bias -> bf16 OUT (same strip overlay; safe: values depend on all Hs reads)
  #pragma unroll
  for (int reg = 0; reg < 4; ++reg) {
    uint16_t* orow = strip + (lk * 4 + reg) * PH;
    #pragma unroll
    for (int n = 0; n < 8; ++n) {
      int col = n * 16 + lrow;
      orow[col] = f2bf(acc2[n][reg] + sb2[col]);
    }
  }
  __syncthreads();

  // segmented reduction over sorted dst: one atomic per (run, col)
  {
    int c = tid & 127;
    int rlo = (tid >> 7) * 32;
    #define LD_OUT(r) __uint_as_float(((uint32_t)A[((r) & ~15) * PA + ((r) & 15) * PH + c]) << 16)
    float run = LD_OUT(rlo);
    int cur = sdst[rlo];
    for (int r = rlo + 1; r < rlo + 32; ++r) {
      int d = sdst[r];           // uniform across wave -> no divergence
      float v = LD_OUT(r);
      if (d != cur) {
        atomicAdd(agg + (size_t)cur * HIDDEN + c, run);
        run = v; cur = d;
      } else {
        run += v;
      }
    }
    atomicAdd(agg + (size_t)cur * HIDDEN + c, run);
    #undef LD_OUT
  }
}

// ---------------- update kernel (overlaid LDS) ----------------

__global__ __launch_bounds__(256) void upd_kernel(
    const float* __restrict__ x, const uint16_t* __restrict__ xb,
    const float* __restrict__ agg,
    const uint16_t* __restrict__ Wu1p, const float* __restrict__ b1,
    const float* __restrict__ g1, const float* __restrict__ be1,
    const uint16_t* __restrict__ Wu2p, const float* __restrict__ b2,
    float* __restrict__ out) {
  __shared__ __align__(16) uint16_t A[64 * PU];
  __shared__ float sb1[128], sg[128], sbe[128], sb2[64];

  const int tid = threadIdx.x;
  const int n0 = blockIdx.x * 64;

  if (tid < 128) { sb1[tid] = b1[tid]; sg[tid] = g1[tid]; }
  else { sbe[tid - 128] = be1[tid - 128]; if (tid < 192) sb2[tid - 128] = b2[tid - 128]; }

  #pragma unroll
  for (int it = 0; it < 2; ++it) {
    int u = tid + it * 256;
    int r = u >> 3, q = u & 7;
    int node = min(n0 + r, N_NODES - 1);
    uint4 vs = *(const uint4*)(xb + (size_t)node * 64 + q * 8);
    *(uint4*)(&A[r * PU + q * 8]) = vs;
  }
  #pragma unroll
  for (int it = 0; it < 8; ++it) {
    int u = tid + it * 256;
    int r = u >> 5, q = u & 31;
    int node = min(n0 + r, N_NODES - 1);
    float4 f = *(const float4*)(agg + (size_t)node * HIDDEN + q * 4);
    ushort4 o;
    o.x = f2bf(f.x); o.y = f2bf(f.y); o.z = f2bf(f.z); o.w = f2bf(f.w);
    *(ushort4*)(&A[r * PU + 64 + q * 4]) = o;
  }
  __syncthreads();

  const int wid = tid >> 6, lane = tid & 63;
  const int lrow = lane & 15, lk = lane >> 4;
  const int r0 = wid * 16;

  // GEMM1: (64x192) @ (192x128)
  f32x4 acc[8] = {};
  const uint16_t* Abase = &A[(r0 + lrow) * PU + lk * 8];
  #pragma unroll
  for (int c = 0; c < 6; ++c) {
    short8 a = *(const short8*)(Abase + c * 32);
    #pragma unroll
    for (int n = 0; n < 8; ++n) {
      short8 b = *(const short8*)(Wu1p + ((size_t)((c * 128) + (n * 16 + lrow)) * 4 + lk) * 8);
      acc[n] = __builtin_amdgcn_mfma_f32_16x16x32_bf16(a, b, acc[n], 0, 0, 0);
    }
  }

  // bias + LN + SiLU -> Hs (strip overlay on A)
  uint16_t* strip = &A[r0 * PU];
  #pragma unroll
  for (int reg = 0; reg < 4; ++reg) {
    float v[8];
    float s = 0.f, ss = 0.f;
    #pragma unroll
    for (int n = 0; n < 8; ++n) {
      v[n] = acc[n][reg] + sb1[n * 16 + lrow];
      s += v[n]; ss += v[n] * v[n];
    }
    #pragma unroll
    for (int m = 1; m <= 8; m <<= 1) {
      s += __shfl_xor(s, m);
      ss += __shfl_xor(ss, m);
    }
    float mu = s * (1.f / 128.f);
    float rstd = rsqrtf(ss * (1.f / 128.f) - mu * mu + LN_EPS);
    uint16_t* hrow = strip + (lk * 4 + reg) * PH;
    #pragma unroll
    for (int n = 0; n < 8; ++n) {
      int col = n * 16 + lrow;
      float h = (v[n] - mu) * rstd * sg[col] + sbe[col];
      h = h / (1.f + __expf(-h));
      hrow[col] = f2bf(h);
    }
  }

  // GEMM2: (64x128) @ (128x64)
  f32x4 acc2[4] = {};
  const uint16_t* Hbase = strip + lrow * PH + lk * 8;
  #pragma unroll
  for (int c = 0; c < 4; ++c) {
    short8 a = *(const short8*)(Hbase + c * 32);
    #pragma unroll
    for (int n = 0; n < 4; ++n) {
      short8 b = *(const short8*)(Wu2p + ((size_t)((c * 64) + (n * 16 + lrow)) * 4 + lk) * 8);
      acc2[n] = __builtin_amdgcn_mfma_f32_16x16x32_bf16(a, b, acc2[n], 0, 0, 0);
    }
  }

  // residual + bias + store f32
  #pragma unroll
  for (int reg = 0; reg < 4; ++reg) {
    int node = n0 + r0 + lk * 4 + reg;
    if (node < N_NODES) {
      #pragma unroll
      for (int n = 0; n < 4; ++n) {
        int col = n * 16 + lrow;
        out[(size_t)node * 64 + col] =
            x[(size_t)node * 64 + col] + acc2[n][reg] + sb2[col];
      }
    }
  }
}

extern "C" void kernel_launch(void* const* d_in, const int* in_sizes, int n_in,
                              void* d_out, int out_size, void* d_ws, size_t ws_size,
                              hipStream_t stream) {
  const float* x   = (const float*)d_in[0];
  const int*   ei  = (const int*)d_in[1];
  const float* ea  = (const float*)d_in[2];
  const float* W1  = (const float*)d_in[3];
  const float* b1  = (const float*)d_in[4];
  const float* g1  = (const float*)d_in[5];
  const float* be1 = (const float*)d_in[6];
  const float* W2  = (const float*)d_in[7];
  const float* b2  = (const float*)d_in[8];
  const float* Wu1 = (const float*)d_in[9];
  const float* bu1 = (const float*)d_in[10];
  const float* gu  = (const float*)d_in[11];
  const float* beu = (const float*)d_in[12];
  const float* Wu2 = (const float*)d_in[13];
  const float* bu2 = (const float*)d_in[14];
  float* out = (float*)d_out;

  char* ws = (char*)d_ws;
  float*    agg    = (float*)ws;                      // 51,200,000
  uint16_t* xb     = (uint16_t*)(ws + 51200000);      // 12,800,000
  uint16_t* W1p    = (uint16_t*)(ws + 64000000);      // 40,960
  uint16_t* W2p    = (uint16_t*)(ws + 64040960);      // 32,768
  uint16_t* Wu1p   = (uint16_t*)(ws + 64073728);      // 49,152
  uint16_t* Wu2p   = (uint16_t*)(ws + 64122880);      // 16,384
  int*      cnt    = (int*)(ws + 64139264);           // 400,000
  int*      offs   = (int*)(ws + 64539264);           // 400,000
  int*      cursor = (int*)(ws + 64939264);           // 400,000
  int*      bsum   = (int*)(ws + 65339264);           // 512
  int*      src_s  = (int*)(ws + 65339776);           // 3,200,000
  int*      dst_s  = (int*)(ws + 68539776);           // 3,200,000
  int*      eid_s  = (int*)(ws + 71739776);           // 3,200,000  (end ~74.9 MB)

  hipMemsetAsync(agg, 0, (size_t)N_NODES * HIDDEN * 4, stream);
  hipMemsetAsync(cnt, 0, (size_t)N_NODES * 4, stream);

  prep_kernel<<<PREP_CVT_BLKS + PREP_HIST_BLKS + 272, 256, 0, stream>>>(
      x, xb, ei, cnt, W1, W1p, W2, W2p, Wu1, Wu1p, Wu2, Wu2p);

  scan_blk<<<NB_SCAN, 256, 0, stream>>>(cnt, offs, bsum);
  scan_top<<<1, 128, 0, stream>>>(bsum);
  scan_add<<<(N_NODES + 255) / 256, 256, 0, stream>>>(offs, bsum, cursor);
  scatter_edges<<<(N_EDGES + 255) / 256, 256, 0, stream>>>(ei, cursor, src_s, dst_s, eid_s);

  msg_kernel<<<N_EDGES / 64, 256, 0, stream>>>(src_s, dst_s, eid_s, ea, xb,
                                               W1p, b1, g1, be1, W2p, b2, agg);
  upd_kernel<<<(N_NODES + 63) / 64, 256, 0, stream>>>(x, xb, agg, Wu1p, bu1, gu, beu,
                                                      Wu2p, bu2, out);
}

// Round 6
// 408.839 us; speedup vs baseline: 1.6947x; 1.1431x over previous
//
#include <hip/hip_runtime.h>
#include <stdint.h>

// MPNN layer, dst-sorted edge processing (R6):
//  - counting-sort edges by dst
//  - msg kernel: 64 sorted edges/block, bf16 MFMA MLP. R2's dedicated-Hs
//    structure (fastest correct variant) shrunk to <40KB LDS -> 4 blocks/CU:
//    A pitch 160 (320B, 16B-aligned), bf16 param staging, bf16 OUT written
//    in-place into the wave's OWN Hs strip (wave-private rows).
//    Final barrier removed: each wave segment-reduces its own 16 rows.
//    NO min-waves launch bound (R3: (256,6) spilled the accumulators,
//    1.7GB scratch; R4's restructure diverged post-timing - reverted).
//  - upd kernel: node MLP + residual (R5 version, passed post-timing).

#define N_NODES 100000
#define N_EDGES 800000
#define NODE_DIM 64
#define EDGE_DIM 32
#define HIDDEN 128
#define LN_EPS 1e-5f

#define PA 160   // msg A-tile pitch (bf16 elems), 160 data cols, 320B rows
#define PH 136   // Hs / OUT pitch (bf16 elems), 128 data cols
#define PU 200   // upd A-tile pitch (bf16 elems), 192 data cols

#define NB_SCAN ((N_NODES + 1023) / 1024)   // 98

typedef __attribute__((ext_vector_type(8))) short short8;
typedef __attribute__((ext_vector_type(4))) float f32x4;

static __device__ __forceinline__ uint16_t f2bf(float f) {
  uint32_t u = __float_as_uint(f);
  return (uint16_t)((u + 0x7FFFu + ((u >> 16) & 1u)) >> 16);
}
static __device__ __forceinline__ float bf2f(uint16_t u) {
  return __uint_as_float(((uint32_t)u) << 16);
}

// ---------------- fused prepass: cvt_x + hist + pack all weights ----------------

#define PREP_CVT_BLKS 6250
#define PREP_HIST_BLKS 3125

__global__ void prep_kernel(const float* __restrict__ x, uint16_t* __restrict__ xb,
                            const int* __restrict__ ei, int* __restrict__ cnt,
                            const float* __restrict__ W1, uint16_t* __restrict__ W1p,
                            const float* __restrict__ W2, uint16_t* __restrict__ W2p,
                            const float* __restrict__ Wu1, uint16_t* __restrict__ Wu1p,
                            const float* __restrict__ Wu2, uint16_t* __restrict__ Wu2p) {
  int b = blockIdx.x;
  if (b < PREP_CVT_BLKS) {
    int i = b * 256 + threadIdx.x;           // quad index
    if (i * 4 < N_NODES * NODE_DIM) {
      float4 f = *(const float4*)(x + (size_t)i * 4);
      ushort4 o;
      o.x = f2bf(f.x); o.y = f2bf(f.y); o.z = f2bf(f.z); o.w = f2bf(f.w);
      *(ushort4*)(xb + (size_t)i * 4) = o;
    }
    return;
  }
  if (b < PREP_CVT_BLKS + PREP_HIST_BLKS) {
    int e = (b - PREP_CVT_BLKS) * 256 + threadIdx.x;
    if (e < N_EDGES) atomicAdd(&cnt[ei[N_EDGES + e]], 1);
    return;
  }
  int i = (b - PREP_CVT_BLKS - PREP_HIST_BLKS) * 256 + threadIdx.x;
  const float* W; uint16_t* dst; int K, C;
  if (i < 20480)      { W = W1;  dst = W1p;  K = 160; C = 128; }
  else if (i < 36864) { W = W2;  dst = W2p;  K = 128; C = 128; i -= 20480; }
  else if (i < 61440) { W = Wu1; dst = Wu1p; K = 192; C = 128; i -= 36864; }
  else if (i < 69632) { W = Wu2; dst = Wu2p; K = 128; C = 64;  i -= 61440; }
  else return;
  int k = i / C, c = i % C;
  dst[(((k >> 5) * C + c) * 4 + ((k >> 3) & 3)) * 8 + (k & 7)] = f2bf(W[i]);
}

// ---------------- counting sort by dst ----------------

__global__ __launch_bounds__(256) void scan_blk(const int* __restrict__ cnt,
                                                int* __restrict__ offs,
                                                int* __restrict__ bsum) {
  __shared__ int wsum[4];
  int tid = threadIdx.x;
  int base = blockIdx.x * 1024 + tid * 4;
  int v0 = 0, v1 = 0, v2 = 0, v3 = 0;
  if (base < N_NODES) v0 = cnt[base];
  if (base + 1 < N_NODES) v1 = cnt[base + 1];
  if (base + 2 < N_NODES) v2 = cnt[base + 2];
  if (base + 3 < N_NODES) v3 = cnt[base + 3];
  int tsum = v0 + v1 + v2 + v3;
  int lane = tid & 63, wid = tid >> 6;
  int s = tsum;
  #pragma unroll
  for (int d = 1; d < 64; d <<= 1) {
    int t = __shfl_up(s, d);
    if (lane >= d) s += t;
  }
  if (lane == 63) wsum[wid] = s;
  __syncthreads();
  int woff = 0;
  for (int w = 0; w < wid; ++w) woff += wsum[w];
  int excl = woff + s - tsum;
  if (base < N_NODES) {
    int run = excl;
    offs[base] = run; run += v0;
    if (base + 1 < N_NODES) { offs[base + 1] = run; run += v1; }
    if (base + 2 < N_NODES) { offs[base + 2] = run; run += v2; }
    if (base + 3 < N_NODES) { offs[base + 3] = run; run += v3; }
  }
  if (tid == 255) bsum[blockIdx.x] = woff + s;
}

__global__ void scan_top(int* __restrict__ bsum) {
  __shared__ int sh[128];
  int tid = threadIdx.x;
  int v = (tid < NB_SCAN) ? bsum[tid] : 0;
  int orig = v;
  sh[tid] = v;
  __syncthreads();
  for (int d = 1; d < 128; d <<= 1) {
    int t = (tid >= d) ? sh[tid - d] : 0;
    __syncthreads();
    v += t;
    sh[tid] = v;
    __syncthreads();
  }
  if (tid < NB_SCAN) bsum[tid] = v - orig;
}

__global__ void scan_add(const int* __restrict__ offs, const int* __restrict__ bsum,
                         int* __restrict__ cursor) {
  int i = blockIdx.x * 256 + threadIdx.x;
  if (i < N_NODES) cursor[i] = offs[i] + bsum[i >> 10];
}

__global__ void scatter_edges(const int* __restrict__ ei, int* __restrict__ cursor,
                              int* __restrict__ src_s, int* __restrict__ dst_s,
                              int* __restrict__ eid_s) {
  int e = blockIdx.x * 256 + threadIdx.x;
  if (e < N_EDGES) {
    int s = ei[e], d = ei[N_EDGES + e];
    int p = atomicAdd(&cursor[d], 1);
    src_s[p] = s; dst_s[p] = d; eid_s[p] = e;
  }
}

// ---------------- message kernel (sorted edges) ----------------

__global__ __launch_bounds__(256) void msg_kernel(
    const int* __restrict__ src_s, const int* __restrict__ dst_s,
    const int* __restrict__ eid_s,
    const float* __restrict__ ea, const uint16_t* __restrict__ xb,
    const uint16_t* __restrict__ W1p, const float* __restrict__ b1,
    const float* __restrict__ g1, const float* __restrict__ be1,
    const uint16_t* __restrict__ W2p, const float* __restrict__ b2,
    float* __restrict__ agg) {
  // LDS: A 20480 + Hs 17408 + idx 768 + bf16 params 1024 = 39680 B -> 4 blk/CU
  __shared__ __align__(16) uint16_t A[64 * PA];
  __shared__ __align__(16) uint16_t Hs[64 * PH];
  __shared__ int ssrc[64], sdst[64], seid[64];
  __shared__ uint16_t sb1h[128], sgh[128], sbeh[128], sb2h[128];

  const int tid = threadIdx.x;
  const int e0 = blockIdx.x * 64;

  if (tid < 64) ssrc[tid] = src_s[e0 + tid];
  else if (tid < 128) sdst[tid - 64] = dst_s[e0 + tid - 64];
  else if (tid < 192) seid[tid - 128] = eid_s[e0 + tid - 128];
  if (tid < 128) { sb1h[tid] = f2bf(b1[tid]); sgh[tid] = f2bf(g1[tid]); }
  else { sbeh[tid - 128] = f2bf(be1[tid - 128]); sb2h[tid - 128] = f2bf(b2[tid - 128]); }
  __syncthreads();

  // gather x[src], x[dst] (bf16 rows, 8x16B) + convert edge_attr row
  #pragma unroll
  for (int it = 0; it < 2; ++it) {
    int u = tid + it * 256;
    int e = u >> 3, q = u & 7;
    uint4 vs = *(const uint4*)(xb + (size_t)ssrc[e] * 64 + q * 8);
    *(uint4*)(&A[e * PA + q * 8]) = vs;
    uint4 vd = *(const uint4*)(xb + (size_t)sdst[e] * 64 + q * 8);
    *(uint4*)(&A[e * PA + 64 + q * 8]) = vd;
    float4 f = *(const float4*)(ea + (size_t)seid[e] * EDGE_DIM + q * 4);
    ushort4 o;
    o.x = f2bf(f.x); o.y = f2bf(f.y); o.z = f2bf(f.z); o.w = f2bf(f.w);
    *(ushort4*)(&A[e * PA + 128 + q * 4]) = o;
  }
  __syncthreads();

  const int wid = tid >> 6, lane = tid & 63;
  const int lrow = lane & 15, lk = lane >> 4;
  const int r0 = wid * 16;

  // GEMM1: (64x160) @ (160x128)
  f32x4 acc[8] = {};
  const uint16_t* Abase = &A[(r0 + lrow) * PA + lk * 8];
  #pragma unroll
  for (int c = 0; c < 5; ++c) {
    short8 a = *(const short8*)(Abase + c * 32);
    #pragma unroll
    for (int n = 0; n < 8; ++n) {
      short8 b = *(const short8*)(W1p + ((size_t)((c * 128) + (n * 16 + lrow)) * 4 + lk) * 8);
      acc[n] = __builtin_amdgcn_mfma_f32_16x16x32_bf16(a, b, acc[n], 0, 0, 0);
    }
  }

  // bias + LayerNorm + SiLU -> Hs rows r0..r0+15 (wave-private)
  #pragma unroll
  for (int reg = 0; reg < 4; ++reg) {
    float v[8];
    float s = 0.f, ss = 0.f;
    #pragma unroll
    for (int n = 0; n < 8; ++n) {
      v[n] = acc[n][reg] + bf2f(sb1h[n * 16 + lrow]);
      s += v[n]; ss += v[n] * v[n];
    }
    #pragma unroll
    for (int m = 1; m <= 8; m <<= 1) {
      s += __shfl_xor(s, m);
      ss += __shfl_xor(ss, m);
    }
    float mu = s * (1.f / 128.f);
    float rstd = rsqrtf(ss * (1.f / 128.f) - mu * mu + LN_EPS);
    uint16_t* hrow = &Hs[(r0 + lk * 4 + reg) * PH];
    #pragma unroll
    for (int n = 0; n < 8; ++n) {
      int col = n * 16 + lrow;
      float h = (v[n] - mu) * rstd * bf2f(sgh[col]) + bf2f(sbeh[col]);
      h = h / (1.f + __expf(-h));
      hrow[col] = f2bf(h);
    }
  }

  // GEMM2: (64x128) @ (128x128); wave reads only its own Hs rows.
  // In-wave LDS write->read ordering handled by compiler lgkmcnt.
  f32x4 acc2[8] = {};
  const uint16_t* Hbase = &Hs[(r0 + lrow) * PH + lk * 8];
  #pragma unroll
  for (int c = 0; c < 4; ++c) {
    short8 a = *(const short8*)(Hbase + c * 32);
    #pragma unroll
    for (int n = 0; n < 8; ++n) {
      short8 b = *(const short8*)(W2p + ((size_t)((c * 128) + (n * 16 + lrow)) * 4 + lk) * 8);
      acc2[n] = __builtin_amdgcn_mfma_f32_16x16x32_bf16(a, b, acc2[n], 0, 0, 0);
    }
  }

  // bias -> bf16 OUT in-place over the wave's own Hs rows (values depend on
  // all of this wave's Hs reads, so no read-after-write hazard).
  #pragma unroll
  for (int reg = 0; reg < 4; ++reg) {
    uint16_t* orow = &Hs[(r0 + lk * 4 + reg) * PH];
    #pragma unroll
    for (int n = 0; n < 8; ++n) {
      int col = n * 16 + lrow;
      orow[col] = f2bf(acc2[n][reg] + bf2f(sb2h[col]));
    }
  }

  // wave-local segmented reduction over this wave's 16 sorted rows.
  // No final barrier needed: no cross-wave LDS reads remain.
  {
    int cur = sdst[r0];
    ushort2 o = *(const ushort2*)&Hs[r0 * PH + lane * 2];
    float run0 = bf2f(o.x), run1 = bf2f(o.y);
    #pragma unroll
    for (int i = 1; i < 16; ++i) {
      int r = r0 + i;
      int d = sdst[r];           // uniform across wave -> no divergence
      ushort2 t = *(const ushort2*)&Hs[r * PH + lane * 2];
      float v0 = bf2f(t.x), v1 = bf2f(t.y);
      if (d != cur) {
        atomicAdd(agg + (size_t)cur * HIDDEN + lane * 2,     run0);
        atomicAdd(agg + (size_t)cur * HIDDEN + lane * 2 + 1, run1);
        run0 = v0; run1 = v1; cur = d;
      } else {
        run0 += v0; run1 += v1;
      }
    }
    atomicAdd(agg + (size_t)cur * HIDDEN + lane * 2,     run0);
    atomicAdd(agg + (size_t)cur * HIDDEN + lane * 2 + 1, run1);
  }
}

// ---------------- update kernel (overlaid LDS, R5 version) ----------------

__global__ __launch_bounds__(256) void upd_kernel(
    const float* __restrict__ x, const uint16_t* __restrict__ xb,
    const float* __restrict__ agg,
    const uint16_t* __restrict__ Wu1p, const float* __restrict__ b1,
    const float* __restrict__ g1, const float* __restrict__ be1,
    const uint16_t* __restrict__ Wu2p, const float* __restrict__ b2,
    float* __restrict__ out) {
  __shared__ __align__(16) uint16_t A[64 * PU];
  __shared__ float sb1[128], sg[128], sbe[128], sb2[64];

  const int tid = threadIdx.x;
  const int n0 = blockIdx.x * 64;

  if (tid < 128) { sb1[tid] = b1[tid]; sg[tid] = g1[tid]; }
  else { sbe[tid - 128] = be1[tid - 128]; if (tid < 192) sb2[tid - 128] = b2[tid - 128]; }

  #pragma unroll
  for (int it = 0; it < 2; ++it) {
    int u = tid + it * 256;
    int r = u >> 3, q = u & 7;
    int node = min(n0 + r, N_NODES - 1);
    uint4 vs = *(const uint4*)(xb + (size_t)node * 64 + q * 8);
    *(uint4*)(&A[r * PU + q * 8]) = vs;
  }
  #pragma unroll
  for (int it = 0; it < 8; ++it) {
    int u = tid + it * 256;
    int r = u >> 5, q = u & 31;
    int node = min(n0 + r, N_NODES - 1);
    float4 f = *(const float4*)(agg + (size_t)node * HIDDEN + q * 4);
    ushort4 o;
    o.x = f2bf(f.x); o.y = f2bf(f.y); o.z = f2bf(f.z); o.w = f2bf(f.w);
    *(ushort4*)(&A[r * PU + 64 + q * 4]) = o;
  }
  __syncthreads();

  const int wid = tid >> 6, lane = tid & 63;
  const int lrow = lane & 15, lk = lane >> 4;
  const int r0 = wid * 16;

  // GEMM1: (64x192) @ (192x128)
  f32x4 acc[8] = {};
  const uint16_t* Abase = &A[(r0 + lrow) * PU + lk * 8];
  #pragma unroll
  for (int c = 0; c < 6; ++c) {
    short8 a = *(const short8*)(Abase + c * 32);
    #pragma unroll
    for (int n = 0; n < 8; ++n) {
      short8 b = *(const short8*)(Wu1p + ((size_t)((c * 128) + (n * 16 + lrow)) * 4 + lk) * 8);
      acc[n] = __builtin_amdgcn_mfma_f32_16x16x32_bf16(a, b, acc[n], 0, 0, 0);
    }
  }

  // bias + LN + SiLU -> Hs (strip overlay on A)
  uint16_t* strip = &A[r0 * PU];
  #pragma unroll
  for (int reg = 0; reg < 4; ++reg) {
    float v[8];
    float s = 0.f, ss = 0.f;
    #pragma unroll
    for (int n = 0; n < 8; ++n) {
      v[n] = acc[n][reg] + sb1[n * 16 + lrow];
      s += v[n]; ss += v[n] * v[n];
    }
    #pragma unroll
    for (int m = 1; m <= 8; m <<= 1) {
      s += __shfl_xor(s, m);
      ss += __shfl_xor(ss, m);
    }
    float mu = s * (1.f / 128.f);
    float rstd = rsqrtf(ss * (1.f / 128.f) - mu * mu + LN_EPS);
    uint16_t* hrow = strip + (lk * 4 + reg) * PH;
    #pragma unroll
    for (int n = 0; n < 8; ++n) {
      int col = n * 16 + lrow;
      float h = (v[n] - mu) * rstd * sg[col] + sbe[col];
      h = h / (1.f + __expf(-h));
      hrow[col] = f2bf(h);
    }
  }

  // GEMM2: (64x128) @ (128x64)
  f32x4 acc2[4] = {};
  const uint16_t* Hbase = strip + lrow * PH + lk * 8;
  #pragma unroll
  for (int c = 0; c < 4; ++c) {
    short8 a = *(const short8*)(Hbase + c * 32);
    #pragma unroll
    for (int n = 0; n < 4; ++n) {
      short8 b = *(const short8*)(Wu2p + ((size_t)((c * 64) + (n * 16 + lrow)) * 4 + lk) * 8);
      acc2[n] = __builtin_amdgcn_mfma_f32_16x16x32_bf16(a, b, acc2[n], 0, 0, 0);
    }
  }

  // residual + bias + store f32
  #pragma unroll
  for (int reg = 0; reg < 4; ++reg) {
    int node = n0 + r0 + lk * 4 + reg;
    if (node < N_NODES) {
      #pragma unroll
      for (int n = 0; n < 4; ++n) {
        int col = n * 16 + lrow;
        out[(size_t)node * 64 + col] =
            x[(size_t)node * 64 + col] + acc2[n][reg] + sb2[col];
      }
    }
  }
}

extern "C" void kernel_launch(void* const* d_in, const int* in_sizes, int n_in,
                              void* d_out, int out_size, void* d_ws, size_t ws_size,
                              hipStream_t stream) {
  const float* x   = (const float*)d_in[0];
  const int*   ei  = (const int*)d_in[1];
  const float* ea  = (const float*)d_in[2];
  const float* W1  = (const float*)d_in[3];
  const float* b1  = (const float*)d_in[4];
  const float* g1  = (const float*)d_in[5];
  const float* be1 = (const float*)d_in[6];
  const float* W2  = (const float*)d_in[7];
  const float* b2  = (const float*)d_in[8];
  const float* Wu1 = (const float*)d_in[9];
  const float* bu1 = (const float*)d_in[10];
  const float* gu  = (const float*)d_in[11];
  const float* beu = (const float*)d_in[12];
  const float* Wu2 = (const float*)d_in[13];
  const float* bu2 = (const float*)d_in[14];
  float* out = (float*)d_out;

  char* ws = (char*)d_ws;
  float*    agg    = (float*)ws;                      // 51,200,000
  uint16_t* xb     = (uint16_t*)(ws + 51200000);      // 12,800,000
  uint16_t* W1p    = (uint16_t*)(ws + 64000000);      // 40,960
  uint16_t* W2p    = (uint16_t*)(ws + 64040960);      // 32,768
  uint16_t* Wu1p   = (uint16_t*)(ws + 64073728);      // 49,152
  uint16_t* Wu2p   = (uint16_t*)(ws + 64122880);      // 16,384
  int*      cnt    = (int*)(ws + 64139264);           // 400,000
  int*      offs   = (int*)(ws + 64539264);           // 400,000
  int*      cursor = (int*)(ws + 64939264);           // 400,000
  int*      bsum   = (int*)(ws + 65339264);           // 512
  int*      src_s  = (int*)(ws + 65339776);           // 3,200,000
  int*      dst_s  = (int*)(ws + 68539776);           // 3,200,000
  int*      eid_s  = (int*)(ws + 71739776);           // 3,200,000  (end ~74.9 MB)

  hipMemsetAsync(agg, 0, (size_t)N_NODES * HIDDEN * 4, stream);
  hipMemsetAsync(cnt, 0, (size_t)N_NODES * 4, stream);

  prep_kernel<<<PREP_CVT_BLKS + PREP_HIST_BLKS + 272, 256, 0, stream>>>(
      x, xb, ei, cnt, W1, W1p, W2, W2p, Wu1, Wu1p, Wu2, Wu2p);

  scan_blk<<<NB_SCAN, 256, 0, stream>>>(cnt, offs, bsum);
  scan_top<<<1, 128, 0, stream>>>(bsum);
  scan_add<<<(N_NODES + 255) / 256, 256, 0, stream>>>(offs, bsum, cursor);
  scatter_edges<<<(N_EDGES + 255) / 256, 256, 0, stream>>>(ei, cursor, src_s, dst_s, eid_s);

  msg_kernel<<<N_EDGES / 64, 256, 0, stream>>>(src_s, dst_s, eid_s, ea, xb,
                                               W1p, b1, g1, be1, W2p, b2, agg);
  upd_kernel<<<(N_NODES + 63) / 64, 256, 0, stream>>>(x, xb, agg, Wu1p, bu1, gu, beu,
                                                      Wu2p, bu2, out);
}